// Round 2
// 660.843 us; speedup vs baseline: 1.1148x; 1.1148x over previous
//
#include <hip/hip_runtime.h>

#define DIMC 1024
#define BATCH 8
#define SEQ 4096
#define BS (BATCH*SEQ)   // 32768
#define PCOL 2051

typedef unsigned short ushort_t;
typedef __attribute__((ext_vector_type(8))) short short8;
typedef __attribute__((ext_vector_type(4))) float f32x4;
typedef __attribute__((ext_vector_type(4))) unsigned short us4;

__device__ __forceinline__ float bf2f(ushort_t u) {
    union { unsigned u32; float f; } v; v.u32 = ((unsigned)u) << 16; return v.f;
}
__device__ __forceinline__ ushort_t f2bf(float f) {
    union { float f; unsigned u; } v; v.f = f;
    unsigned r = v.u + 0x7fffu + ((v.u >> 16) & 1u);
    return (ushort_t)(r >> 16);
}
__device__ __forceinline__ float gelu_exact(float x) {
    return 0.5f * x * (1.0f + erff(x * 0.7071067811865475f));
}
__device__ __forceinline__ void gld16(const ushort_t* g, ushort_t* l) {
    __builtin_amdgcn_global_load_lds(
        (const __attribute__((address_space(1))) unsigned int*)g,
        (__attribute__((address_space(3))) unsigned int*)l, 16, 0, 0);
}

// ---------------- elementwise f32 -> bf16 ----------------
__global__ void cvt_f32_bf16(const float* __restrict__ src, ushort_t* __restrict__ dst, int n) {
    int i = (blockIdx.x * 256 + threadIdx.x) * 4;
    if (i >= n) return;
    f32x4 v = *(const f32x4*)(src + i);
    us4 o;
    #pragma unroll
    for (int j = 0; j < 4; j++) o[j] = f2bf(v[j]);
    *(us4*)(dst + i) = o;
}

// ---------------- transpose + cvt: dst[n*K + k] = src[k*ld + n] ----------------
__global__ void transpose_cvt(const float* __restrict__ src, ushort_t* __restrict__ dst,
                              int ld, int K) {
    __shared__ float tile[32][33];
    int tx = threadIdx.x & 31, ty = threadIdx.x >> 5;   // 32 x 8
    int n0 = blockIdx.x * 32, k0 = blockIdx.y * 32;
    #pragma unroll
    for (int j = 0; j < 4; j++)
        tile[ty + j * 8][tx] = src[(size_t)(k0 + ty + j * 8) * ld + n0 + tx];
    __syncthreads();
    #pragma unroll
    for (int j = 0; j < 4; j++)
        dst[(size_t)(n0 + ty + j * 8) * K + k0 + tx] = f2bf(tile[tx][ty + j * 8]);
}

// ---------------- pack gate weight columns: wg[j*1024+d] = W_in[d*PCOL + 2048+j] ----------------
__global__ void pack_gatesw(const float* __restrict__ W_in, float* __restrict__ wg) {
    int d = blockIdx.x * 256 + threadIdx.x;
    if (d >= 1024) return;
    const float* p = W_in + (size_t)d * PCOL + 2048;
    wg[d] = p[0]; wg[1024 + d] = p[1]; wg[2048 + d] = p[2];
}

// ---------------- fused: ibf = bf16(input); gates[row] = input[row] . wg + b_in ----------------
__global__ void cvt_gates(const float* __restrict__ input, const float* __restrict__ wg,
                          const float* __restrict__ b_in, ushort_t* __restrict__ ibf,
                          float* __restrict__ gates) {
    int row = blockIdx.x, tid = threadIdx.x;
    int lane = tid & 63, wave = tid >> 6;
    size_t base = (size_t)row * 1024 + tid * 4;
    f32x4 v = *(const f32x4*)(input + base);
    us4 o;
    #pragma unroll
    for (int j = 0; j < 4; j++) o[j] = f2bf(v[j]);
    *(us4*)(ibf + base) = o;
    f32x4 w0v = *(const f32x4*)(wg + tid * 4);
    f32x4 w1v = *(const f32x4*)(wg + 1024 + tid * 4);
    f32x4 w2v = *(const f32x4*)(wg + 2048 + tid * 4);
    float a0 = 0, a1 = 0, a2 = 0;
    #pragma unroll
    for (int j = 0; j < 4; j++) { a0 += v[j] * w0v[j]; a1 += v[j] * w1v[j]; a2 += v[j] * w2v[j]; }
    #pragma unroll
    for (int off = 32; off; off >>= 1) {
        a0 += __shfl_down(a0, off, 64);
        a1 += __shfl_down(a1, off, 64);
        a2 += __shfl_down(a2, off, 64);
    }
    __shared__ float red[4][3];
    if (lane == 0) { red[wave][0] = a0; red[wave][1] = a1; red[wave][2] = a2; }
    __syncthreads();
    if (tid == 0) {
        gates[row * 4 + 0] = red[0][0] + red[1][0] + red[2][0] + red[3][0] + b_in[2048];
        gates[row * 4 + 1] = red[0][1] + red[1][1] + red[2][1] + red[3][1] + b_in[2049];
        gates[row * 4 + 2] = red[0][2] + red[1][2] + red[2][2] + red[3][2] + b_in[2050];
    }
}

// ============ 256x256 8-phase bf16 MFMA GEMM (T1+T2+T3+T4+T5) ============
// C[M,N] = A[M,K] @ Bt[N,K]^T + bias, with epilogue MODEs as before.
// 512 threads = 8 waves (2M x 4N), per-wave 128x64 out, BK=64, dbuf LDS 128 KiB.
// st_16x32 swizzle: 16B-chunk(r,k8) = ((r>>4)*2 + (k8>>2))*64 + (r&15)*4
//                                     + ((k8&3) ^ (((r>>3)&1)<<1))
// Staged via linear global_load_lds dest + pre-swizzled per-lane global source;
// ds_read uses the same swizzle (rule 21: both-sides).
template<int MODE>
__global__ __launch_bounds__(512, 2)
void gemm256(const ushort_t* __restrict__ A, const ushort_t* __restrict__ Bt,
             const float* __restrict__ bias, void* __restrict__ C,
             const ushort_t* __restrict__ Q, const float* __restrict__ gates,
             const float* __restrict__ vb, int K, int ldc, int ldq, int nbx) {
    __shared__ ushort_t lA[2][16384];
    __shared__ ushort_t lB[2][16384];
    const int tid = threadIdx.x, lane = tid & 63, wave = tid >> 6;
    const int lr = lane & 15, kq = lane >> 4;
    const int wrm = wave >> 2, wrn = wave & 3;

    // T1: XCD-aware bijective block swizzle
    const int nwg = gridDim.x, bid = blockIdx.x;
    const int q8 = nwg >> 3, r8 = nwg & 7;
    const int xcd = bid & 7, linb = bid >> 3;
    const int wgid = (xcd < r8 ? xcd * (q8 + 1) : r8 * (q8 + 1) + (xcd - r8) * q8) + linb;
    const int bn = wgid % nbx, bm = wgid / nbx;

    const ushort_t* Ag = A + (size_t)bm * 256 * K;
    const ushort_t* Bg = Bt + (size_t)bn * 256 * K;

    // swizzled fragment read base (ushort index): chunk col XOR'd by row-bit-3
    const int xsw = kq ^ (((lr >> 3) & 1) << 1);
    const int fBase = lr * 32 + xsw * 8;

    // staging: per-thread inverse-swizzled global source offsets (ushort units),
    // wave-uniform LDS chunk bases. [h = half (128 rows)][j = load index]
    int srOff[2][2], ldsC[2][2];
    #pragma unroll
    for (int h = 0; h < 2; h++)
        #pragma unroll
        for (int j = 0; j < 2; j++) {
            int c = h * 1024 + j * 512 + tid;           // linear 16B-chunk id in tile
            int sub = c >> 6, rl = (c >> 2) & 15, cc = c & 3;
            int r  = ((sub >> 1) << 4) | rl;
            int k8 = ((sub & 1) << 2) | (cc ^ (((rl >> 3) & 1) << 1));
            srOff[h][j] = r * K + k8 * 8;
            ldsC[h][j]  = (h * 1024 + j * 512 + (wave << 6)) << 3;
        }

    f32x4 acc[8][4];
    #pragma unroll
    for (int i = 0; i < 8; i++)
        #pragma unroll
        for (int j = 0; j < 4; j++)
            #pragma unroll
            for (int r = 0; r < 4; r++) acc[i][j][r] = 0.f;

    short8 af[2][2], bfr[4][2];

#define STG(ARR, bb, G, kt, h) do { \
    gld16((G) + (size_t)(kt) * 64 + srOff[h][0], &ARR[bb][ldsC[h][0]]); \
    gld16((G) + (size_t)(kt) * 64 + srOff[h][1], &ARR[bb][ldsC[h][1]]); \
} while (0)

// One phase: {ds_read subtile || stage 1 half-tile} -> barrier -> lgkmcnt(0)
// -> setprio(1) 16 MFMA setprio(0) -> [vmcnt(4) once per K-tile] -> barrier.
// Counted vmcnt(4): the 4 newest stage-loads (this K-tile's P3/P4 or P7/P8)
// stay in flight across the barrier; per-wave wait BEFORE barrier => all
// waves' needed stages landed after barrier.
#define PHASE(bb, qq, STAGE_STMT, DOVM) do { \
    if ((qq) == 0) { \
        _Pragma("unroll") \
        for (int nt = 0; nt < 4; nt++) { \
            bfr[nt][0] = *(const short8*)&lB[bb][fBase + ((wrn * 4 + nt) * 2 + 0) * 512]; \
            bfr[nt][1] = *(const short8*)&lB[bb][fBase + ((wrn * 4 + nt) * 2 + 1) * 512]; \
        } \
    } \
    af[0][0] = *(const short8*)&lA[bb][fBase + ((wrm * 8 + (qq) * 2 + 0) * 2 + 0) * 512]; \
    af[0][1] = *(const short8*)&lA[bb][fBase + ((wrm * 8 + (qq) * 2 + 0) * 2 + 1) * 512]; \
    af[1][0] = *(const short8*)&lA[bb][fBase + ((wrm * 8 + (qq) * 2 + 1) * 2 + 0) * 512]; \
    af[1][1] = *(const short8*)&lA[bb][fBase + ((wrm * 8 + (qq) * 2 + 1) * 2 + 1) * 512]; \
    STAGE_STMT; \
    __builtin_amdgcn_s_barrier(); \
    asm volatile("s_waitcnt lgkmcnt(0)" ::: "memory"); \
    __builtin_amdgcn_s_setprio(1); \
    _Pragma("unroll") \
    for (int mi = 0; mi < 2; mi++) \
        _Pragma("unroll") \
        for (int nt = 0; nt < 4; nt++) { \
            acc[(qq) * 2 + mi][nt] = __builtin_amdgcn_mfma_f32_16x16x32_bf16( \
                af[mi][0], bfr[nt][0], acc[(qq) * 2 + mi][nt], 0, 0, 0); \
            acc[(qq) * 2 + mi][nt] = __builtin_amdgcn_mfma_f32_16x16x32_bf16( \
                af[mi][1], bfr[nt][1], acc[(qq) * 2 + mi][nt], 0, 0, 0); \
        } \
    __builtin_amdgcn_s_setprio(0); \
    if (DOVM) asm volatile("s_waitcnt vmcnt(4)" ::: "memory"); \
    __builtin_amdgcn_s_barrier(); \
} while (0)

    // prologue: tile0 A+B -> buf0, tile1 B -> buf1 (A(1) comes in P1/P2 of iter 0)
    STG(lA, 0, Ag, 0, 0); STG(lA, 0, Ag, 0, 1);
    STG(lB, 0, Bg, 0, 0); STG(lB, 0, Bg, 0, 1);
    STG(lB, 1, Bg, 1, 0); STG(lB, 1, Bg, 1, 1);
    asm volatile("s_waitcnt vmcnt(4)" ::: "memory");   // tile0 landed; B(1) in flight
    __builtin_amdgcn_s_barrier();

    // Stage schedule per iter (tiles t=2i in buf0, t+1 in buf1):
    //  P1/P2: A(t+1)->lA[1] (free: last read prev P8)   P3/P4: B(t+2)->lB[0] (free after P1)
    //  P5/P6: A(t+2)->lA[0] (free after P4)             P7/P8: B(t+3)->lB[1] (free after P5)
    // Last iter: t2/t3 clamp to KT-1 -> re-stages tile15 data into dead regions
    // (keeps vmcnt arithmetic uniform, no branches).
    const int KT = K >> 6;
    for (int it = 0; it < (K >> 7); it++) {
        int t1 = 2 * it + 1;
        int t2 = 2 * it + 2; if (t2 > KT - 1) t2 = KT - 1;
        int t3 = 2 * it + 3; if (t3 > KT - 1) t3 = KT - 1;
        PHASE(0, 0, STG(lA, 1, Ag, t1, 0), 0);
        PHASE(0, 1, STG(lA, 1, Ag, t1, 1), 0);
        PHASE(0, 2, STG(lB, 0, Bg, t2, 0), 0);
        PHASE(0, 3, STG(lB, 0, Bg, t2, 1), 1);
        PHASE(1, 0, STG(lA, 0, Ag, t2, 0), 0);
        PHASE(1, 1, STG(lA, 0, Ag, t2, 1), 0);
        PHASE(1, 2, STG(lB, 1, Bg, t3, 0), 0);
        PHASE(1, 3, STG(lB, 1, Bg, t3, 1), 1);
    }
#undef PHASE
#undef STG
    // Drain all in-flight global_load_lds before the block can exit: stray
    // writes landing after s_endpgm would corrupt a successor workgroup's LDS.
    asm volatile("s_waitcnt vmcnt(0)" ::: "memory");

    // epilogue (same math as previous kernel; bitwise-identical accumulation order)
    const int bbatch = (bm * 256) >> 12;   // batch index (uniform, SEQ=4096)
    #pragma unroll
    for (int mt = 0; mt < 8; mt++) {
        #pragma unroll
        for (int r = 0; r < 4; r++) {
            int row = bm * 256 + wrm * 128 + mt * 16 + kq * 4 + r;
            size_t rowc = (size_t)row * ldc;
            float g2;
            if (MODE == 1) g2 = gates[row * 4 + 2];
            #pragma unroll
            for (int nt = 0; nt < 4; nt++) {
                int col = bn * 256 + wrn * 64 + nt * 16 + lr;
                float v = acc[mt][nt][r] + bias[col];
                if (MODE == 1) {
                    v += g2 * vb[bbatch * 1024 + col];
                    v *= bf2f(Q[(size_t)row * ldq + col]);
                }
                if (MODE == 2) ((float*)C)[rowc + col] = v;
                else           ((ushort_t*)C)[rowc + col] = f2bf(v);
            }
        }
    }
}

// ---------------- fused dwconv14 -> gelu -> dwconv18 -> gelu -> P = c0*g0 + c1*g1 ----------------
__global__ __launch_bounds__(256)
void dwconv_fused(const ushort_t* __restrict__ proj,   // ld=2048, ctx at col offset 1024
                  const float* __restrict__ w0, const float* __restrict__ b0,
                  const float* __restrict__ w1, const float* __restrict__ b1,
                  const float* __restrict__ gates,
                  ushort_t* __restrict__ P, float* __restrict__ G) {
    __shared__ float xc[94 * 64];
    __shared__ float x0[81 * 64];
    __shared__ float gl[2][64];
    __shared__ float rs[256];
    const int tid = threadIdx.x;
    const int s0 = blockIdx.x * 64, d0 = blockIdx.y * 64, b = blockIdx.z;
    for (int c = tid; c < 94 * 8; c += 256) {
        int r = c >> 3, dd = (c & 7) * 8;
        int s = s0 - 14 + r;
        float f[8];
        if (s >= 0 && s < SEQ) {
            short8 u = *(const short8*)&proj[(size_t)(b * SEQ + s) * 2048 + 1024 + d0 + dd];
            #pragma unroll
            for (int j = 0; j < 8; j++) f[j] = bf2f((ushort_t)u[j]);
        } else {
            #pragma unroll
            for (int j = 0; j < 8; j++) f[j] = 0.f;
        }
        f32x4 v0 = {f[0], f[1], f[2], f[3]}, v1 = {f[4], f[5], f[6], f[7]};
        *(f32x4*)&xc[r * 64 + dd] = v0;
        *(f32x4*)&xc[r * 64 + dd + 4] = v1;
    }
    if (tid < 64) gl[0][tid] = gates[(size_t)(b * SEQ + s0 + tid) * 4 + 0];
    else if (tid < 128) gl[1][tid - 64] = gates[(size_t)(b * SEQ + s0 + tid - 64) * 4 + 1];
    const int d = tid & 63, sc = tid >> 6;
    float wr0[14], wr1[18];
    #pragma unroll
    for (int t = 0; t < 14; t++) wr0[t] = w0[(size_t)(d0 + d) * 14 + t];
    float bb0 = b0[d0 + d];
    #pragma unroll
    for (int t = 0; t < 18; t++) wr1[t] = w1[(size_t)(d0 + d) * 18 + t];
    float bb1 = b1[d0 + d];
    __syncthreads();
    {
        float xw[34];
        int r0 = sc * 20;
        #pragma unroll
        for (int r = 0; r < 34; r++) xw[r] = xc[(r0 + r) * 64 + d];
        #pragma unroll
        for (int i = 0; i < 21; i++) {
            int rr = r0 + i;
            int s = s0 - 8 + rr;
            float acc = bb0;
            #pragma unroll
            for (int t = 0; t < 14; t++) acc += wr0[t] * xw[i + t];
            x0[rr * 64 + d] = (s >= 0 && s < SEQ) ? gelu_exact(acc) : 0.f;
        }
    }
    __syncthreads();
    float xw1[33];
    #pragma unroll
    for (int r = 0; r < 33; r++) xw1[r] = x0[(sc * 16 + r) * 64 + d];
    float psum = 0.f;
    #pragma unroll
    for (int i = 0; i < 16; i++) {
        float acc = bb1;
        #pragma unroll
        for (int t = 0; t < 18; t++) acc += wr1[t] * xw1[i + t];
        float c1 = gelu_exact(acc);
        psum += c1;
        float c0v = xw1[i + 8];
        int sl = sc * 16 + i;
        float pv = c0v * gl[0][sl] + c1 * gl[1][sl];
        P[(size_t)(b * SEQ + s0 + sl) * 1024 + d0 + d] = f2bf(pv);
    }
    rs[tid] = psum;
    __syncthreads();
    if (sc == 0)
        atomicAdd(&G[b * 1024 + d0 + d], rs[d] + rs[64 + d] + rs[128 + d] + rs[192 + d]);
}

// ---------------- v[b,o] = sum_c gelu(G[b,c]/SEQ) * Wctx[o,c] ----------------
__global__ __launch_bounds__(256)
void gemv_v(const float* __restrict__ G, const ushort_t* __restrict__ wctxB,
            float* __restrict__ v) {
    __shared__ float gg[1024];
    const int tid = threadIdx.x, b = blockIdx.y;
    for (int i = tid; i < 1024; i += 256)
        gg[i] = gelu_exact(G[b * 1024 + i] * (1.0f / (float)SEQ));
    __syncthreads();
    const int w = tid >> 6, lane = tid & 63;
    const int o = blockIdx.x * 4 + w;
    const ushort_t* wr = wctxB + (size_t)o * 1024;
    float acc = 0.f;
    #pragma unroll
    for (int j = 0; j < 16; j++)
        acc += gg[j * 64 + lane] * bf2f(wr[j * 64 + lane]);
    #pragma unroll
    for (int off = 32; off; off >>= 1) acc += __shfl_down(acc, off, 64);
    if (lane == 0) v[b * 1024 + o] = acc;
}

extern "C" void kernel_launch(void* const* d_in, const int* in_sizes, int n_in,
                              void* d_out, int out_size, void* d_ws, size_t ws_size,
                              hipStream_t stream) {
    const float* input = (const float*)d_in[0];
    const float* W_in  = (const float*)d_in[1];
    const float* b_in  = (const float*)d_in[2];
    const float* w0    = (const float*)d_in[3];
    const float* b0    = (const float*)d_in[4];
    const float* w1    = (const float*)d_in[5];
    const float* b1    = (const float*)d_in[6];
    const float* W_ctx = (const float*)d_in[7];
    const float* b_ctx = (const float*)d_in[8];
    const float* W_out = (const float*)d_in[9];
    const float* b_out = (const float*)d_in[10];

    char* ws = (char*)d_ws;
    size_t o = 0;
    ushort_t* ibf   = (ushort_t*)(ws + o); o += (size_t)BS * 1024 * 2;   // input bf16, reused as P
    ushort_t* proj  = (ushort_t*)(ws + o); o += (size_t)BS * 2048 * 2;   // [query | ctx] bf16
    ushort_t* Y     = (ushort_t*)(ws + o); o += (size_t)BS * 1024 * 2;
    float*    gates = (float*)   (ws + o); o += (size_t)BS * 4 * 4;
    float*    G     = (float*)   (ws + o); o += (size_t)BATCH * 1024 * 4;
    float*    v     = (float*)   (ws + o); o += (size_t)BATCH * 1024 * 4;
    float*    wg    = (float*)   (ws + o); o += (size_t)3 * 1024 * 4;
    ushort_t* winT  = (ushort_t*)(ws + o); o += (size_t)2048 * 1024 * 2;
    ushort_t* wctxB = (ushort_t*)(ws + o); o += (size_t)1024 * 1024 * 2;
    ushort_t* woutT = (ushort_t*)(ws + o); o += (size_t)1024 * 1024 * 2;
    ushort_t* P = ibf;   // safe: ibf last read by gemm0; dwconv_fused writes P after

    hipMemsetAsync(G, 0, BATCH * 1024 * sizeof(float), stream);
    // weight prep
    pack_gatesw<<<4, 256, 0, stream>>>(W_in, wg);
    transpose_cvt<<<dim3(2048 / 32, 1024 / 32), 256, 0, stream>>>(W_in, winT, PCOL, 1024);
    cvt_f32_bf16<<<1024 * 1024 / 4 / 256, 256, 0, stream>>>(W_ctx, wctxB, 1024 * 1024);
    transpose_cvt<<<dim3(1024 / 32, 1024 / 32), 256, 0, stream>>>(W_out, woutT, 1024, 1024);
    // input cvt + gates GEMV (fp32)
    cvt_gates<<<BS, 256, 0, stream>>>(input, wg, b_in, ibf, gates);
    // proj[:, 0:2048] = input @ W_in[:, 0:2048] + b_in   (M=32768, N=2048, K=1024)
    gemm256<0><<<dim3(8 * (BS / 256)), 512, 0, stream>>>(ibf, winT, b_in, proj,
        nullptr, nullptr, nullptr, 1024, 2048, 0, 8);
    // fused conv chain -> P (= c0*g0 + c1*g1), G (= sum_s c1)
    dwconv_fused<<<dim3(SEQ / 64, 16, BATCH), 256, 0, stream>>>(proj, w0, b0, w1, b1, gates, P, G);
    // v[b,:] = gelu(G/SEQ) @ Wctx^T
    gemv_v<<<dim3(256, BATCH), 256, 0, stream>>>(G, wctxB, v);
    // Y = query * (P @ Wctx^T + b_ctx + g2 (x) v)
    gemm256<1><<<dim3(4 * (BS / 256)), 512, 0, stream>>>(P, wctxB, b_ctx, Y,
        proj, gates, v, 1024, 1024, 2048, 4);
    // out = Y @ W_out + b_out  (fp32)
    gemm256<2><<<dim3(4 * (BS / 256)), 512, 0, stream>>>(Y, woutT, b_out, d_out,
        nullptr, nullptr, nullptr, 1024, 1024, 0, 4);
}